// Round 9
// baseline (278.047 us; speedup 1.0000x reference)
//
#include <hip/hip_runtime.h>
#include <cstdint>

#define BDIM 8192
#define DDIM 128
#define JS 32

// ws layout (bytes)
#define ZH_OFF 0
#define ZM_OFF (2 * 1024 * 1024)
#define RL_OFF (4 * 1024 * 1024)
#define CNT_OFF (RL_OFF + BDIM * 4)          // int cnt
#define FC_OFF (CNT_OFF + 64)                // int fin_counter
#define P_OFF (RL_OFF + 65536)               // float2 P2[BDIM][JS] = 2 MB

typedef __attribute__((ext_vector_type(8))) short bf16x8;   // 8 bf16 = 4 VGPRs
typedef __attribute__((ext_vector_type(4))) float f32x4;

__device__ __forceinline__ short f2bf(float f) {            // RTN-even fp32->bf16
  unsigned u = __float_as_uint(f);
  unsigned r = (u + 0x7fffu + ((u >> 16) & 1u)) >> 16;
  return (short)r;
}
__device__ __forceinline__ float bf2f(short h) {
  return __uint_as_float(((unsigned)(unsigned short)h) << 16);
}
__device__ __forceinline__ void gload_lds16(const void* g, void* l) {
  __builtin_amdgcn_global_load_lds(
      (const __attribute__((address_space(1))) unsigned int*)g,
      (__attribute__((address_space(3))) unsigned int*)l, 16, 0, 0);
}

// Fragment-tiled Z layout (shorts): element (row,k) at
//   (row>>4)*2048 + (k>>5)*512 + ((k>>3)&3)*128 + (row&15)*8 + (k&7)
// -> one MFMA fragment (16 rows x 8 k) = contiguous 1 KB per wave; a
//    (j16,kc) unit is 1 KB linear in BOTH global and LDS (direct DMA copy).
//
// 2-pass split: zh = bf16(z), zm = bf16(2z - zh).
//   0.5*(zh.zm' + zm.zh') = zh.zh' + zh.zl' + zl.zh'  (the 3-pass sum)
// extra error ~2^-9 on cos (~0.02 on s) — guard: absmax must stay < 0.01.

// Kernel 1: blocks 0..511 normalize + zh/zm split (tiled layout);
// block 512 compacts censor==1 rows (prefix scan) and zeroes fin_counter.
__global__ __launch_bounds__(256) void ck_prep(
    const float* __restrict__ emb, const int* __restrict__ censor,
    short* __restrict__ ZhT, short* __restrict__ ZmT,
    int* __restrict__ rowlist, int* __restrict__ cnt, int* __restrict__ fc)
{
  __shared__ float zl[16][132];
  __shared__ float pr[16][16];
  __shared__ float inv[16];
  __shared__ int wtot[4], woff[4];

  const int t = threadIdx.x;
  if (blockIdx.x == 512) {               // ---- compact branch ----
    const int lane = t & 63, wv = t >> 6;
    const int4* c4 = (const int4*)(censor + t * 32);
    unsigned fm = 0;
#pragma unroll
    for (int q = 0; q < 8; ++q) {
      const int4 v = c4[q];
      fm |= (unsigned)(v.x == 1) << (q * 4 + 0);
      fm |= (unsigned)(v.y == 1) << (q * 4 + 1);
      fm |= (unsigned)(v.z == 1) << (q * 4 + 2);
      fm |= (unsigned)(v.w == 1) << (q * 4 + 3);
    }
    const int loc = __popc(fm);
    int sc = loc;                         // inclusive wave scan
#pragma unroll
    for (int m = 1; m < 64; m <<= 1) {
      const int u = __shfl_up(sc, m, 64);
      if (lane >= m) sc += u;
    }
    if (lane == 63) wtot[wv] = sc;
    __syncthreads();
    if (t == 0) {
      int run = 0;
#pragma unroll
      for (int i = 0; i < 4; ++i) { woff[i] = run; run += wtot[i]; }
      fc[0] = 0;                          // zero finalize counter (ws poisoned)
    }
    __syncthreads();
    int off = woff[wv] + sc - loc;
    for (int u = 0; u < 32; ++u)
      if ((fm >> u) & 1) rowlist[off++] = t * 32 + u;
    if (t == 255) cnt[0] = off;
    return;
  }

  // ---- normalize branch: one 16-row tile per block ----
  const int R = blockIdx.x;
  const int r16 = t >> 4, seg = t & 15;
  const float4* src = (const float4*)(emb + (size_t)(R * 16 + r16) * DDIM + seg * 8);
  const float4 v0 = src[0], v1 = src[1];
  float* zr = &zl[r16][seg * 8];
  zr[0] = v0.x; zr[1] = v0.y; zr[2] = v0.z; zr[3] = v0.w;
  zr[4] = v1.x; zr[5] = v1.y; zr[6] = v1.z; zr[7] = v1.w;
  pr[r16][seg] = v0.x * v0.x + v0.y * v0.y + v0.z * v0.z + v0.w * v0.w +
                 v1.x * v1.x + v1.y * v1.y + v1.z * v1.z + v1.w * v1.w;
  __syncthreads();
  if (t < 16) {
    float ss = 0.f;
#pragma unroll
    for (int s = 0; s < 16; ++s) ss += pr[t][s];
    inv[t] = 1.0f / fmaxf(sqrtf(ss), 1e-12f);   // F.normalize semantics
  }
  __syncthreads();
  const int kc = t >> 6, hf = (t >> 4) & 3, rw = t & 15;
  const float iv = inv[rw];
  const float* zs = &zl[rw][(kc * 4 + hf) * 8];
  short hs[8], ms[8];
#pragma unroll
  for (int j = 0; j < 8; ++j) {
    const float z = zs[j] * iv;
    const short h = f2bf(z);
    hs[j] = h;
    ms[j] = f2bf(2.f * z - bf2f(h));      // zm = bf16(2z - zh)
  }
  const int dst = R * 2048 + t * 8;
  *(bf16x8*)(ZhT + dst) = *(const bf16x8*)hs;
  *(bf16x8*)(ZmT + dst) = *(const bf16x8*)ms;
}

// Kernel 2: MFMA sim + masked exp-sums + fused last-block finalize.
// Block = 128 i (4 waves x 32) x 256 j (4 st-steps of 64). Wave tile 32i x 64j.
// 2-pass: acc = Ah*Bm + Am*Bh (scale 5 in epilogue). A hi+m register-resident;
// tJ preloaded for all 4 st-steps -> NO global access in the st-loop. B hi/m
// staged to 2x32KB LDS dbuf via global_load_lds; one barrier per st-step.
__global__ __launch_bounds__(256, 2) void ck_main(
    const short* __restrict__ ZhT, const short* __restrict__ ZmT,
    const int* __restrict__ rowlist, const int* __restrict__ cntp,
    const int* __restrict__ times, float2* __restrict__ P2,
    int* __restrict__ fc, float* __restrict__ out)
{
  __shared__ __align__(16) char lds[65536];
  const int cnt = *cntp;
  const int t = threadIdx.x;
  const int b = blockIdx.x;
  const int it = b >> 5;                   // i-tile (128 rows, compacted)
  const int js = b & 31;                   // j-split (256 j)
  const int lane = t & 63;
  const int w = t >> 6;
  const int half = lane >> 4;
  const int ll = lane & 15;
  const int jR0 = js * 16;                 // base j16 unit

  if (it * 128 < cnt) {                    // block-uniform guard
    // A-frag rows (A rows m = ll), a = 0..1 -> wave covers 32 i-rows
    int rbase[2];
#pragma unroll
    for (int a = 0; a < 2; ++a) {
      int c = it * 128 + w * 32 + a * 16 + ll;
      if (c >= cnt) c = cnt - 1;           // duplicate valid row; masked at store
      const int r = rowlist[c];
      rbase[a] = (r >> 4) * 2048 + (r & 15) * 8;
    }
    bf16x8 ah[2][4], am[2][4];             // A hi+m resident (64 VGPR)
#pragma unroll
    for (int a = 0; a < 2; ++a)
#pragma unroll
      for (int kc = 0; kc < 4; ++kc) {
        ah[a][kc] = *(const bf16x8*)(ZhT + rbase[a] + kc * 512 + half * 128);
        am[a][kc] = *(const bf16x8*)(ZmT + rbase[a] + kc * 512 + half * 128);
      }

    // packed per-(a,r) meta for C/D rows (row = half*4 + r):
    // meta = (ti+364)<<16 | gi ; invalid: gi=0xFFFF, taP=50000 (tests false)
    int meta[2][4];
#pragma unroll
    for (int a = 0; a < 2; ++a)
#pragma unroll
      for (int r = 0; r < 4; ++r) {
        const int idx = it * 128 + w * 32 + a * 16 + half * 4 + r;
        const bool vi = idx < cnt;
        const int gi = rowlist[vi ? idx : 0];
        const int taP = vi ? (times[gi] + 364) : 50000;
        meta[a][r] = (taP << 16) | (vi ? gi : 0xFFFF);
      }

    // preload tJ for ALL st-steps (16 regs) -> no global loads in st-loop
    int tJ[4][4];
#pragma unroll
    for (int st = 0; st < 4; ++st)
#pragma unroll
      for (int bb = 0; bb < 4; ++bb)
        tJ[st][bb] = times[js * 256 + st * 64 + bb * 16 + ll];

    float sd[2][4] = {{0.f}}, sn[2][4] = {{0.f}};

    // prologue: stage st=0 into buffer 0 (wave w copies 1KB chunks w*8..w*8+7)
    {
      const int c0 = w * 8;
#pragma unroll
      for (int u = 0; u < 8; ++u) {
        const int c = c0 + u, cp = c & 15;
        const short* src = (c < 16) ? ZhT : ZmT;
        const short* gp = src + (size_t)(jR0 + (cp >> 2)) * 2048 + (cp & 3) * 512 + lane * 8;
        gload_lds16(gp, lds + ((c < 16) ? 0 : 16384) + cp * 1024);
      }
    }

    for (int st = 0; st < 4; ++st) {
      __syncthreads();                     // buf[st&1] resident (drains vmcnt)
      if (st < 3) {                        // stage st+1 into other buffer;
        const int pB = ((st + 1) & 1) * 32768;   // drained by NEXT barrier
        const int c0 = w * 8;
#pragma unroll
        for (int u = 0; u < 8; ++u) {
          const int c = c0 + u, cp = c & 15;
          const short* src = (c < 16) ? ZhT : ZmT;
          const short* gp = src + (size_t)(jR0 + (st + 1) * 4 + (cp >> 2)) * 2048 + (cp & 3) * 512 + lane * 8;
          gload_lds16(gp, lds + pB + ((c < 16) ? 0 : 16384) + cp * 1024);
        }
      }

      const char* L = lds + (st & 1) * 32768;
      f32x4 acc[2][4];
#pragma unroll
      for (int a = 0; a < 2; ++a)
#pragma unroll
        for (int bb = 0; bb < 4; ++bb) acc[a][bb] = (f32x4){0.f, 0.f, 0.f, 0.f};

#pragma unroll
      for (int kc = 0; kc < 4; ++kc) {
#pragma unroll
        for (int bb = 0; bb < 4; ++bb) {   // b-major: one B hi/m pair live
          const bf16x8 bhv = *(const bf16x8*)(L + bb * 4096 + kc * 1024 + lane * 16);
          const bf16x8 bmv = *(const bf16x8*)(L + 16384 + bb * 4096 + kc * 1024 + lane * 16);
          acc[0][bb] = __builtin_amdgcn_mfma_f32_16x16x32_bf16(ah[0][kc], bmv, acc[0][bb], 0, 0, 0);
          acc[1][bb] = __builtin_amdgcn_mfma_f32_16x16x32_bf16(ah[1][kc], bmv, acc[1][bb], 0, 0, 0);
          acc[0][bb] = __builtin_amdgcn_mfma_f32_16x16x32_bf16(am[0][kc], bhv, acc[0][bb], 0, 0, 0);
          acc[1][bb] = __builtin_amdgcn_mfma_f32_16x16x32_bf16(am[1][kc], bhv, acc[1][bb], 0, 0, 0);
        }
      }

      // epilogue: s = acc*5 (= cos*10); fixed-offset exp-sums exp(s-10)
      const int jb = js * 256 + st * 64;
#pragma unroll
      for (int a = 0; a < 2; ++a)
#pragma unroll
        for (int r = 0; r < 4; ++r) {
          const int m_ = meta[a][r];
          const int gi = m_ & 0xFFFF;
          const unsigned taP = ((unsigned)m_) >> 16;
          float d = 0.f, n = 0.f;
#pragma unroll
          for (int bb = 0; bb < 4; ++bb) {
            const int jgb = jb + bb * 16 + ll;
            float pv = __expf(fmaf(acc[a][bb][r], 5.f, -10.f));
            pv = (gi == jgb) ? 0.f : pv;                 // diagonal mask
            d += pv;
            // |ti-tj|<365  <=>  (u32)(ti+364-tj) <= 728
            n += ((unsigned)(taP - (unsigned)tJ[st][bb]) <= 728u) ? pv : 0.f;
          }
          sd[a][r] += d;
          sn[a][r] += n;
        }
    }

    // reduce over ll (lane bits 0..3); one float2 store per valid row
#pragma unroll
    for (int a = 0; a < 2; ++a)
#pragma unroll
      for (int r = 0; r < 4; ++r) {
        float d = sd[a][r], n = sn[a][r];
#pragma unroll
        for (int m = 1; m <= 8; m <<= 1) {
          d += __shfl_xor(d, m, 64);
          n += __shfl_xor(n, m, 64);
        }
        const int idx = it * 128 + w * 32 + a * 16 + half * 4 + r;
        if (ll == 0 && idx < cnt) P2[(size_t)idx * JS + js] = make_float2(d, n);
      }
  }

  // ---- fused finalize: last block to arrive reduces P2 -> out ----
  __threadfence();                         // release this block's P2 stores
  __syncthreads();
  int* flag = (int*)(lds + 2048);
  if (t == 0) *flag = (atomicAdd(fc, 1) == (int)gridDim.x - 1);
  __syncthreads();
  if (*flag) {
    __threadfence();                       // acquire all blocks' P2 stores
    float lsum = 0.f, lcnt = 0.f;
    for (int idx = t; idx < cnt; idx += 256) {
      const float4* p = (const float4*)(P2 + (size_t)idx * JS);  // 256 B
      float d = 0.f, n = 0.f;
#pragma unroll
      for (int u = 0; u < 16; ++u) {
        const float4 v = p[u];
        d += v.x + v.z;
        n += v.y + v.w;
      }
      if (n > 0.f) { lsum += logf(d) - logf(n); lcnt += 1.f; }
    }
    float* s1 = (float*)lds;               // LDS free for reuse here
    float* s2 = (float*)(lds + 1024);
    s1[t] = lsum; s2[t] = lcnt;
    __syncthreads();
    for (int s = 128; s > 0; s >>= 1) {
      if (t < s) { s1[t] += s1[t + s]; s2[t] += s2[t + s]; }
      __syncthreads();
    }
    if (t == 0) out[0] = (s2[0] > 0.f) ? s1[0] / fmaxf(s2[0], 1.f) : 0.f;
  }
}

extern "C" void kernel_launch(void* const* d_in, const int* in_sizes, int n_in,
                              void* d_out, int out_size, void* d_ws, size_t ws_size,
                              hipStream_t stream) {
  const float* emb  = (const float*)d_in[0];
  const int* times  = (const int*)d_in[1];
  const int* censor = (const int*)d_in[2];
  float* out = (float*)d_out;

  char* ws = (char*)d_ws;
  short* ZhT    = (short*)(ws + ZH_OFF);
  short* ZmT    = (short*)(ws + ZM_OFF);
  int* rowlist  = (int*)(ws + RL_OFF);
  int* cntp     = (int*)(ws + CNT_OFF);
  int* fc       = (int*)(ws + FC_OFF);
  float2* P2    = (float2*)(ws + P_OFF);

  ck_prep<<<513, 256, 0, stream>>>(emb, censor, ZhT, ZmT, rowlist, cntp, fc);
  ck_main<<<64 * 32, 256, 0, stream>>>(ZhT, ZmT, rowlist, cntp, times, P2, fc, out);
}

// Round 10
// 267.768 us; speedup vs baseline: 1.0384x; 1.0384x over previous
//
#include <hip/hip_runtime.h>
#include <cstdint>

#define BDIM 8192
#define DDIM 128
#define JS 32

// ws layout (bytes)
#define ZH_OFF 0
#define ZM_OFF (2 * 1024 * 1024)
#define RL_OFF (4 * 1024 * 1024)
#define CNT_OFF (RL_OFF + BDIM * 4)          // int cnt
#define FC_OFF (CNT_OFF + 64)                // int fin_counter
#define P_OFF (RL_OFF + 65536)               // float2 P2[BDIM][JS] = 2 MB

typedef __attribute__((ext_vector_type(8))) short bf16x8;   // 8 bf16 = 4 VGPRs
typedef __attribute__((ext_vector_type(4))) float f32x4;

__device__ __forceinline__ short f2bf(float f) {            // RTN-even fp32->bf16
  unsigned u = __float_as_uint(f);
  unsigned r = (u + 0x7fffu + ((u >> 16) & 1u)) >> 16;
  return (short)r;
}
__device__ __forceinline__ float bf2f(short h) {
  return __uint_as_float(((unsigned)(unsigned short)h) << 16);
}
__device__ __forceinline__ void gload_lds16(const void* g, void* l) {
  __builtin_amdgcn_global_load_lds(
      (const __attribute__((address_space(1))) unsigned int*)g,
      (__attribute__((address_space(3))) unsigned int*)l, 16, 0, 0);
}

// Fragment-tiled Z layout (shorts): element (row,k) at
//   (row>>4)*2048 + (k>>5)*512 + ((k>>3)&3)*128 + (row&15)*8 + (k&7)
// -> one MFMA fragment (16 rows x 8 k) = contiguous 1 KB per wave; a
//    (j16,kc) unit is 1 KB linear in BOTH global and LDS (direct DMA copy).
//
// 2-pass split: zh = bf16(z), zm = bf16(2z - zh).
//   0.5*(zh.zm' + zm.zh') = zh.zh' + zh.zl' + zl.zh'  (validated R9: absmax 0.0)
//
// MEASURED RULE (R3/R5/R7/R9): __launch_bounds__(256,2) caps arch VGPR at 128
// -> silent scratch spill for this loop's ~150-reg state (WRITE_SIZE balloons).
// ck_main uses plain __launch_bounds__(256); LDS (64KB) still caps 2 blocks/CU.

// Kernel 1: blocks 0..511 normalize + zh/zm split (tiled layout);
// block 512 compacts censor==1 rows (prefix scan) and zeroes fin_counter.
__global__ __launch_bounds__(256) void ck_prep(
    const float* __restrict__ emb, const int* __restrict__ censor,
    short* __restrict__ ZhT, short* __restrict__ ZmT,
    int* __restrict__ rowlist, int* __restrict__ cnt, int* __restrict__ fc)
{
  __shared__ float zl[16][132];
  __shared__ float pr[16][16];
  __shared__ float inv[16];
  __shared__ int wtot[4], woff[4];

  const int t = threadIdx.x;
  if (blockIdx.x == 512) {               // ---- compact branch ----
    const int lane = t & 63, wv = t >> 6;
    const int4* c4 = (const int4*)(censor + t * 32);
    unsigned fm = 0;
#pragma unroll
    for (int q = 0; q < 8; ++q) {
      const int4 v = c4[q];
      fm |= (unsigned)(v.x == 1) << (q * 4 + 0);
      fm |= (unsigned)(v.y == 1) << (q * 4 + 1);
      fm |= (unsigned)(v.z == 1) << (q * 4 + 2);
      fm |= (unsigned)(v.w == 1) << (q * 4 + 3);
    }
    const int loc = __popc(fm);
    int sc = loc;                         // inclusive wave scan
#pragma unroll
    for (int m = 1; m < 64; m <<= 1) {
      const int u = __shfl_up(sc, m, 64);
      if (lane >= m) sc += u;
    }
    if (lane == 63) wtot[wv] = sc;
    __syncthreads();
    if (t == 0) {
      int run = 0;
#pragma unroll
      for (int i = 0; i < 4; ++i) { woff[i] = run; run += wtot[i]; }
      fc[0] = 0;                          // zero finalize counter (ws poisoned)
    }
    __syncthreads();
    int off = woff[wv] + sc - loc;
    for (int u = 0; u < 32; ++u)
      if ((fm >> u) & 1) rowlist[off++] = t * 32 + u;
    if (t == 255) cnt[0] = off;
    return;
  }

  // ---- normalize branch: one 16-row tile per block ----
  const int R = blockIdx.x;
  const int r16 = t >> 4, seg = t & 15;
  const float4* src = (const float4*)(emb + (size_t)(R * 16 + r16) * DDIM + seg * 8);
  const float4 v0 = src[0], v1 = src[1];
  float* zr = &zl[r16][seg * 8];
  zr[0] = v0.x; zr[1] = v0.y; zr[2] = v0.z; zr[3] = v0.w;
  zr[4] = v1.x; zr[5] = v1.y; zr[6] = v1.z; zr[7] = v1.w;
  pr[r16][seg] = v0.x * v0.x + v0.y * v0.y + v0.z * v0.z + v0.w * v0.w +
                 v1.x * v1.x + v1.y * v1.y + v1.z * v1.z + v1.w * v1.w;
  __syncthreads();
  if (t < 16) {
    float ss = 0.f;
#pragma unroll
    for (int s = 0; s < 16; ++s) ss += pr[t][s];
    inv[t] = 1.0f / fmaxf(sqrtf(ss), 1e-12f);   // F.normalize semantics
  }
  __syncthreads();
  const int kc = t >> 6, hf = (t >> 4) & 3, rw = t & 15;
  const float iv = inv[rw];
  const float* zs = &zl[rw][(kc * 4 + hf) * 8];
  short hs[8], ms[8];
#pragma unroll
  for (int j = 0; j < 8; ++j) {
    const float z = zs[j] * iv;
    const short h = f2bf(z);
    hs[j] = h;
    ms[j] = f2bf(2.f * z - bf2f(h));      // zm = bf16(2z - zh)
  }
  const int dst = R * 2048 + t * 8;
  *(bf16x8*)(ZhT + dst) = *(const bf16x8*)hs;
  *(bf16x8*)(ZmT + dst) = *(const bf16x8*)ms;
}

// Kernel 2: MFMA sim + masked exp-sums + fused last-block finalize.
// Block = 128 i (4 waves x 32) x 256 j (4 st-steps of 64). Wave tile 32i x 64j.
// 2-pass: acc = Ah*Bm + Am*Bh (scale 5 in epilogue). A hi+m register-resident;
// tJ preloaded for all 4 st-steps -> NO global access in the st-loop. B hi/m
// staged to 2x32KB LDS dbuf via global_load_lds; one barrier per st-step.
__global__ __launch_bounds__(256) void ck_main(
    const short* __restrict__ ZhT, const short* __restrict__ ZmT,
    const int* __restrict__ rowlist, const int* __restrict__ cntp,
    const int* __restrict__ times, float2* __restrict__ P2,
    int* __restrict__ fc, float* __restrict__ out)
{
  __shared__ __align__(16) char lds[65536];
  const int cnt = *cntp;
  const int t = threadIdx.x;
  const int b = blockIdx.x;
  const int it = b >> 5;                   // i-tile (128 rows, compacted)
  const int js = b & 31;                   // j-split (256 j)
  const int lane = t & 63;
  const int w = t >> 6;
  const int half = lane >> 4;
  const int ll = lane & 15;
  const int jR0 = js * 16;                 // base j16 unit

  if (it * 128 < cnt) {                    // block-uniform guard
    // A-frag rows (A rows m = ll), a = 0..1 -> wave covers 32 i-rows
    int rbase[2];
#pragma unroll
    for (int a = 0; a < 2; ++a) {
      int c = it * 128 + w * 32 + a * 16 + ll;
      if (c >= cnt) c = cnt - 1;           // duplicate valid row; masked at store
      const int r = rowlist[c];
      rbase[a] = (r >> 4) * 2048 + (r & 15) * 8;
    }
    bf16x8 ah[2][4], am[2][4];             // A hi+m resident (64 VGPR)
#pragma unroll
    for (int a = 0; a < 2; ++a)
#pragma unroll
      for (int kc = 0; kc < 4; ++kc) {
        ah[a][kc] = *(const bf16x8*)(ZhT + rbase[a] + kc * 512 + half * 128);
        am[a][kc] = *(const bf16x8*)(ZmT + rbase[a] + kc * 512 + half * 128);
      }

    // packed per-(a,r) meta for C/D rows (row = half*4 + r):
    // meta = (ti+364)<<16 | gi ; invalid: gi=0xFFFF, taP=50000 (tests false)
    int meta[2][4];
#pragma unroll
    for (int a = 0; a < 2; ++a)
#pragma unroll
      for (int r = 0; r < 4; ++r) {
        const int idx = it * 128 + w * 32 + a * 16 + half * 4 + r;
        const bool vi = idx < cnt;
        const int gi = rowlist[vi ? idx : 0];
        const int taP = vi ? (times[gi] + 364) : 50000;
        meta[a][r] = (taP << 16) | (vi ? gi : 0xFFFF);
      }

    // preload tJ for ALL st-steps (16 regs) -> no global loads in st-loop
    int tJ[4][4];
#pragma unroll
    for (int st = 0; st < 4; ++st)
#pragma unroll
      for (int bb = 0; bb < 4; ++bb)
        tJ[st][bb] = times[js * 256 + st * 64 + bb * 16 + ll];

    float sd[2][4] = {{0.f}}, sn[2][4] = {{0.f}};

    // prologue: stage st=0 into buffer 0 (wave w copies 1KB chunks w*8..w*8+7)
    {
      const int c0 = w * 8;
#pragma unroll
      for (int u = 0; u < 8; ++u) {
        const int c = c0 + u, cp = c & 15;
        const short* src = (c < 16) ? ZhT : ZmT;
        const short* gp = src + (size_t)(jR0 + (cp >> 2)) * 2048 + (cp & 3) * 512 + lane * 8;
        gload_lds16(gp, lds + ((c < 16) ? 0 : 16384) + cp * 1024);
      }
    }

    for (int st = 0; st < 4; ++st) {
      __syncthreads();                     // buf[st&1] resident (drains vmcnt)
      if (st < 3) {                        // stage st+1 into other buffer;
        const int pB = ((st + 1) & 1) * 32768;   // drained by NEXT barrier
        const int c0 = w * 8;
#pragma unroll
        for (int u = 0; u < 8; ++u) {
          const int c = c0 + u, cp = c & 15;
          const short* src = (c < 16) ? ZhT : ZmT;
          const short* gp = src + (size_t)(jR0 + (st + 1) * 4 + (cp >> 2)) * 2048 + (cp & 3) * 512 + lane * 8;
          gload_lds16(gp, lds + pB + ((c < 16) ? 0 : 16384) + cp * 1024);
        }
      }

      const char* L = lds + (st & 1) * 32768;
      f32x4 acc[2][4];
#pragma unroll
      for (int a = 0; a < 2; ++a)
#pragma unroll
        for (int bb = 0; bb < 4; ++bb) acc[a][bb] = (f32x4){0.f, 0.f, 0.f, 0.f};

#pragma unroll
      for (int kc = 0; kc < 4; ++kc) {
#pragma unroll
        for (int bb = 0; bb < 4; ++bb) {   // b-major: one B hi/m pair live
          const bf16x8 bhv = *(const bf16x8*)(L + bb * 4096 + kc * 1024 + lane * 16);
          const bf16x8 bmv = *(const bf16x8*)(L + 16384 + bb * 4096 + kc * 1024 + lane * 16);
          acc[0][bb] = __builtin_amdgcn_mfma_f32_16x16x32_bf16(ah[0][kc], bmv, acc[0][bb], 0, 0, 0);
          acc[1][bb] = __builtin_amdgcn_mfma_f32_16x16x32_bf16(ah[1][kc], bmv, acc[1][bb], 0, 0, 0);
          acc[0][bb] = __builtin_amdgcn_mfma_f32_16x16x32_bf16(am[0][kc], bhv, acc[0][bb], 0, 0, 0);
          acc[1][bb] = __builtin_amdgcn_mfma_f32_16x16x32_bf16(am[1][kc], bhv, acc[1][bb], 0, 0, 0);
        }
      }

      // epilogue: s = acc*5 (= cos*10); fixed-offset exp-sums exp(s-10)
      const int jb = js * 256 + st * 64;
#pragma unroll
      for (int a = 0; a < 2; ++a)
#pragma unroll
        for (int r = 0; r < 4; ++r) {
          const int m_ = meta[a][r];
          const int gi = m_ & 0xFFFF;
          const unsigned taP = ((unsigned)m_) >> 16;
          float d = 0.f, n = 0.f;
#pragma unroll
          for (int bb = 0; bb < 4; ++bb) {
            const int jgb = jb + bb * 16 + ll;
            float pv = __expf(fmaf(acc[a][bb][r], 5.f, -10.f));
            pv = (gi == jgb) ? 0.f : pv;                 // diagonal mask
            d += pv;
            // |ti-tj|<365  <=>  (u32)(ti+364-tj) <= 728
            n += ((unsigned)(taP - (unsigned)tJ[st][bb]) <= 728u) ? pv : 0.f;
          }
          sd[a][r] += d;
          sn[a][r] += n;
        }
    }

    // reduce over ll (lane bits 0..3); one float2 store per valid row
#pragma unroll
    for (int a = 0; a < 2; ++a)
#pragma unroll
      for (int r = 0; r < 4; ++r) {
        float d = sd[a][r], n = sn[a][r];
#pragma unroll
        for (int m = 1; m <= 8; m <<= 1) {
          d += __shfl_xor(d, m, 64);
          n += __shfl_xor(n, m, 64);
        }
        const int idx = it * 128 + w * 32 + a * 16 + half * 4 + r;
        if (ll == 0 && idx < cnt) P2[(size_t)idx * JS + js] = make_float2(d, n);
      }
  }

  // ---- fused finalize: last block to arrive reduces P2 -> out ----
  __threadfence();                         // release this block's P2 stores
  __syncthreads();
  int* flag = (int*)(lds + 2048);
  if (t == 0) *flag = (atomicAdd(fc, 1) == (int)gridDim.x - 1);
  __syncthreads();
  if (*flag) {
    __threadfence();                       // acquire all blocks' P2 stores
    float lsum = 0.f, lcnt = 0.f;
    for (int idx = t; idx < cnt; idx += 256) {
      const float4* p = (const float4*)(P2 + (size_t)idx * JS);  // 256 B
      float d = 0.f, n = 0.f;
#pragma unroll
      for (int u = 0; u < 16; ++u) {
        const float4 v = p[u];
        d += v.x + v.z;
        n += v.y + v.w;
      }
      if (n > 0.f) { lsum += logf(d) - logf(n); lcnt += 1.f; }
    }
    float* s1 = (float*)lds;               // LDS free for reuse here
    float* s2 = (float*)(lds + 1024);
    s1[t] = lsum; s2[t] = lcnt;
    __syncthreads();
    for (int s = 128; s > 0; s >>= 1) {
      if (t < s) { s1[t] += s1[t + s]; s2[t] += s2[t + s]; }
      __syncthreads();
    }
    if (t == 0) out[0] = (s2[0] > 0.f) ? s1[0] / fmaxf(s2[0], 1.f) : 0.f;
  }
}

extern "C" void kernel_launch(void* const* d_in, const int* in_sizes, int n_in,
                              void* d_out, int out_size, void* d_ws, size_t ws_size,
                              hipStream_t stream) {
  const float* emb  = (const float*)d_in[0];
  const int* times  = (const int*)d_in[1];
  const int* censor = (const int*)d_in[2];
  float* out = (float*)d_out;

  char* ws = (char*)d_ws;
  short* ZhT    = (short*)(ws + ZH_OFF);
  short* ZmT    = (short*)(ws + ZM_OFF);
  int* rowlist  = (int*)(ws + RL_OFF);
  int* cntp     = (int*)(ws + CNT_OFF);
  int* fc       = (int*)(ws + FC_OFF);
  float2* P2    = (float2*)(ws + P_OFF);

  ck_prep<<<513, 256, 0, stream>>>(emb, censor, ZhT, ZmT, rowlist, cntp, fc);
  ck_main<<<64 * 32, 256, 0, stream>>>(ZhT, ZmT, rowlist, cntp, times, P2, fc, out);
}

// Round 11
// 126.998 us; speedup vs baseline: 2.1894x; 2.1084x over previous
//
#include <hip/hip_runtime.h>
#include <cstdint>

#define BDIM 8192
#define DDIM 128
#define JS 32

// ws layout (bytes)
#define ZH_OFF 0
#define ZM_OFF (2 * 1024 * 1024)
#define RL_OFF (4 * 1024 * 1024)
#define CNT_OFF (RL_OFF + BDIM * 4)          // int cnt
#define FC_OFF (CNT_OFF + 64)                // int fin_counter
#define P_OFF (RL_OFF + 65536)               // float2 P2[BDIM][JS] = 2 MB
#define PART_OFF (P_OFF + BDIM * JS * 8)     // float2 part[32]

typedef __attribute__((ext_vector_type(8))) short bf16x8;   // 8 bf16 = 4 VGPRs
typedef __attribute__((ext_vector_type(4))) float f32x4;

__device__ __forceinline__ short f2bf(float f) {            // RTN-even fp32->bf16
  unsigned u = __float_as_uint(f);
  unsigned r = (u + 0x7fffu + ((u >> 16) & 1u)) >> 16;
  return (short)r;
}
__device__ __forceinline__ float bf2f(short h) {
  return __uint_as_float(((unsigned)(unsigned short)h) << 16);
}
__device__ __forceinline__ void gload_lds16(const void* g, void* l) {
  __builtin_amdgcn_global_load_lds(
      (const __attribute__((address_space(1))) unsigned int*)g,
      (__attribute__((address_space(3))) unsigned int*)l, 16, 0, 0);
}

// Fragment-tiled Z layout (shorts): element (row,k) at
//   (row>>4)*2048 + (k>>5)*512 + ((k>>3)&3)*128 + (row&15)*8 + (k&7)
// -> one MFMA fragment (16 rows x 8 k) = contiguous 1 KB per wave; a
//    (j16,kc) unit is 1 KB linear in BOTH global and LDS (direct DMA copy).
//
// 2-pass split: zh = bf16(z), zm = bf16(2z - zh).
//   0.5*(zh.zm' + zm.zh') = zh.zh' + zh.zl' + zl.zh'  (validated R9/R10: absmax 0.0)
//
// MEASURED RULES:
//  - __launch_bounds__(256,2) caps arch VGPR at 128 -> silent spill (R3/5/7/9).
//    ck_main uses plain __launch_bounds__(256).
//  - Fusing the last-block finalize (threadfence in all 2048 blocks) cost
//    ~150us (R8 vs R10 A/B). Finalize stays a separate 32-block kernel.
//  - Occupancy, not in-block pipelining, hides the barrier drain (m97/m114):
//    single 32KB LDS buffer -> 3 blocks/CU (vs dbuf 64KB -> 2).

// Kernel 1: blocks 0..511 normalize + zh/zm split (tiled layout);
// block 512 compacts censor==1 rows (prefix scan) and zeroes fin_counter.
__global__ __launch_bounds__(256) void ck_prep(
    const float* __restrict__ emb, const int* __restrict__ censor,
    short* __restrict__ ZhT, short* __restrict__ ZmT,
    int* __restrict__ rowlist, int* __restrict__ cnt, int* __restrict__ fc)
{
  __shared__ float zl[16][132];
  __shared__ float pr[16][16];
  __shared__ float inv[16];
  __shared__ int wtot[4], woff[4];

  const int t = threadIdx.x;
  if (blockIdx.x == 512) {               // ---- compact branch ----
    const int lane = t & 63, wv = t >> 6;
    const int4* c4 = (const int4*)(censor + t * 32);
    unsigned fm = 0;
#pragma unroll
    for (int q = 0; q < 8; ++q) {
      const int4 v = c4[q];
      fm |= (unsigned)(v.x == 1) << (q * 4 + 0);
      fm |= (unsigned)(v.y == 1) << (q * 4 + 1);
      fm |= (unsigned)(v.z == 1) << (q * 4 + 2);
      fm |= (unsigned)(v.w == 1) << (q * 4 + 3);
    }
    const int loc = __popc(fm);
    int sc = loc;                         // inclusive wave scan
#pragma unroll
    for (int m = 1; m < 64; m <<= 1) {
      const int u = __shfl_up(sc, m, 64);
      if (lane >= m) sc += u;
    }
    if (lane == 63) wtot[wv] = sc;
    __syncthreads();
    if (t == 0) {
      int run = 0;
#pragma unroll
      for (int i = 0; i < 4; ++i) { woff[i] = run; run += wtot[i]; }
      fc[0] = 0;                          // zero finalize counter (ws poisoned)
    }
    __syncthreads();
    int off = woff[wv] + sc - loc;
    for (int u = 0; u < 32; ++u)
      if ((fm >> u) & 1) rowlist[off++] = t * 32 + u;
    if (t == 255) cnt[0] = off;
    return;
  }

  // ---- normalize branch: one 16-row tile per block ----
  const int R = blockIdx.x;
  const int r16 = t >> 4, seg = t & 15;
  const float4* src = (const float4*)(emb + (size_t)(R * 16 + r16) * DDIM + seg * 8);
  const float4 v0 = src[0], v1 = src[1];
  float* zr = &zl[r16][seg * 8];
  zr[0] = v0.x; zr[1] = v0.y; zr[2] = v0.z; zr[3] = v0.w;
  zr[4] = v1.x; zr[5] = v1.y; zr[6] = v1.z; zr[7] = v1.w;
  pr[r16][seg] = v0.x * v0.x + v0.y * v0.y + v0.z * v0.z + v0.w * v0.w +
                 v1.x * v1.x + v1.y * v1.y + v1.z * v1.z + v1.w * v1.w;
  __syncthreads();
  if (t < 16) {
    float ss = 0.f;
#pragma unroll
    for (int s = 0; s < 16; ++s) ss += pr[t][s];
    inv[t] = 1.0f / fmaxf(sqrtf(ss), 1e-12f);   // F.normalize semantics
  }
  __syncthreads();
  const int kc = t >> 6, hf = (t >> 4) & 3, rw = t & 15;
  const float iv = inv[rw];
  const float* zs = &zl[rw][(kc * 4 + hf) * 8];
  short hs[8], ms[8];
#pragma unroll
  for (int j = 0; j < 8; ++j) {
    const float z = zs[j] * iv;
    const short h = f2bf(z);
    hs[j] = h;
    ms[j] = f2bf(2.f * z - bf2f(h));      // zm = bf16(2z - zh)
  }
  const int dst = R * 2048 + t * 8;
  *(bf16x8*)(ZhT + dst) = *(const bf16x8*)hs;
  *(bf16x8*)(ZmT + dst) = *(const bf16x8*)ms;
}

// Kernel 2: MFMA sim + masked exp-sums. Block = 128 i (4 waves x 32) x 256 j
// (4 st-steps of 64). Wave tile 32i x 64j. 2-pass: acc = Ah*Bm + Am*Bh
// (scale 5 in epilogue). A hi+m register-resident; tJ preloaded -> no global
// access in the st-loop. B hi/m staged per st into a SINGLE 32KB LDS buffer
// (m97-style 2-barrier cadence); 3 blocks/CU hide the staging latency.
__global__ __launch_bounds__(256) void ck_main(
    const short* __restrict__ ZhT, const short* __restrict__ ZmT,
    const int* __restrict__ rowlist, const int* __restrict__ cntp,
    const int* __restrict__ times, float2* __restrict__ P2)
{
  __shared__ __align__(16) char lds[32768];   // Bh 16KB @0, Bm 16KB @16384
  const int cnt = *cntp;
  const int t = threadIdx.x;
  const int b = blockIdx.x;
  const int it = b >> 5;                   // i-tile (128 rows, compacted)
  const int js = b & 31;                   // j-split (256 j)
  if (it * 128 >= cnt) return;
  const int lane = t & 63;
  const int w = t >> 6;
  const int half = lane >> 4;
  const int ll = lane & 15;
  const int jR0 = js * 16;                 // base j16 unit

  // A-frag rows (A rows m = ll), a = 0..1 -> wave covers 32 i-rows
  int rbase[2];
#pragma unroll
  for (int a = 0; a < 2; ++a) {
    int c = it * 128 + w * 32 + a * 16 + ll;
    if (c >= cnt) c = cnt - 1;             // duplicate valid row; masked at store
    const int r = rowlist[c];
    rbase[a] = (r >> 4) * 2048 + (r & 15) * 8;
  }
  bf16x8 ah[2][4], am[2][4];               // A hi+m resident (64 VGPR)
#pragma unroll
  for (int a = 0; a < 2; ++a)
#pragma unroll
    for (int kc = 0; kc < 4; ++kc) {
      ah[a][kc] = *(const bf16x8*)(ZhT + rbase[a] + kc * 512 + half * 128);
      am[a][kc] = *(const bf16x8*)(ZmT + rbase[a] + kc * 512 + half * 128);
    }

  // packed per-(a,r) meta for C/D rows (row = half*4 + r):
  // meta = (ti+364)<<16 | gi ; invalid: gi=0xFFFF, taP=50000 (tests false)
  int meta[2][4];
#pragma unroll
  for (int a = 0; a < 2; ++a)
#pragma unroll
    for (int r = 0; r < 4; ++r) {
      const int idx = it * 128 + w * 32 + a * 16 + half * 4 + r;
      const bool vi = idx < cnt;
      const int gi = rowlist[vi ? idx : 0];
      const int taP = vi ? (times[gi] + 364) : 50000;
      meta[a][r] = (taP << 16) | (vi ? gi : 0xFFFF);
    }

  // preload tJ for ALL st-steps (16 regs) -> no global loads in st-loop
  int tJ[4][4];
#pragma unroll
  for (int st = 0; st < 4; ++st)
#pragma unroll
    for (int bb = 0; bb < 4; ++bb)
      tJ[st][bb] = times[js * 256 + st * 64 + bb * 16 + ll];

  float sd[2][4] = {{0.f}}, sn[2][4] = {{0.f}};

  for (int st = 0; st < 4; ++st) {
    __syncthreads();                       // previous st's readers done
    {  // stage this st's B hi/m: 32 x 1KB chunks, wave w copies w*8..w*8+7
      const int c0 = w * 8;
#pragma unroll
      for (int u = 0; u < 8; ++u) {
        const int c = c0 + u, cp = c & 15;
        const short* src = (c < 16) ? ZhT : ZmT;
        const short* gp = src + (size_t)(jR0 + st * 4 + (cp >> 2)) * 2048 + (cp & 3) * 512 + lane * 8;
        gload_lds16(gp, lds + ((c < 16) ? 0 : 16384) + cp * 1024);
      }
    }
    __syncthreads();                       // vmcnt drained -> B resident

    f32x4 acc[2][4];
#pragma unroll
    for (int a = 0; a < 2; ++a)
#pragma unroll
      for (int bb = 0; bb < 4; ++bb) acc[a][bb] = (f32x4){0.f, 0.f, 0.f, 0.f};

#pragma unroll
    for (int kc = 0; kc < 4; ++kc) {
#pragma unroll
      for (int bb = 0; bb < 4; ++bb) {     // b-major: one B hi/m pair live
        const bf16x8 bhv = *(const bf16x8*)(lds + bb * 4096 + kc * 1024 + lane * 16);
        const bf16x8 bmv = *(const bf16x8*)(lds + 16384 + bb * 4096 + kc * 1024 + lane * 16);
        acc[0][bb] = __builtin_amdgcn_mfma_f32_16x16x32_bf16(ah[0][kc], bmv, acc[0][bb], 0, 0, 0);
        acc[1][bb] = __builtin_amdgcn_mfma_f32_16x16x32_bf16(ah[1][kc], bmv, acc[1][bb], 0, 0, 0);
        acc[0][bb] = __builtin_amdgcn_mfma_f32_16x16x32_bf16(am[0][kc], bhv, acc[0][bb], 0, 0, 0);
        acc[1][bb] = __builtin_amdgcn_mfma_f32_16x16x32_bf16(am[1][kc], bhv, acc[1][bb], 0, 0, 0);
      }
    }

    // epilogue: s = acc*5 (= cos*10); fixed-offset exp-sums exp(s-10)
    const int jb = js * 256 + st * 64;
#pragma unroll
    for (int a = 0; a < 2; ++a)
#pragma unroll
      for (int r = 0; r < 4; ++r) {
        const int m_ = meta[a][r];
        const int gi = m_ & 0xFFFF;
        const unsigned taP = ((unsigned)m_) >> 16;
        float d = 0.f, n = 0.f;
#pragma unroll
        for (int bb = 0; bb < 4; ++bb) {
          const int jgb = jb + bb * 16 + ll;
          float pv = __expf(fmaf(acc[a][bb][r], 5.f, -10.f));
          pv = (gi == jgb) ? 0.f : pv;                 // diagonal mask
          d += pv;
          // |ti-tj|<365  <=>  (u32)(ti+364-tj) <= 728
          n += ((unsigned)(taP - (unsigned)tJ[st][bb]) <= 728u) ? pv : 0.f;
        }
        sd[a][r] += d;
        sn[a][r] += n;
      }
  }

  // reduce over ll (lane bits 0..3); one float2 store per valid row
#pragma unroll
  for (int a = 0; a < 2; ++a)
#pragma unroll
    for (int r = 0; r < 4; ++r) {
      float d = sd[a][r], n = sn[a][r];
#pragma unroll
      for (int m = 1; m <= 8; m <<= 1) {
        d += __shfl_xor(d, m, 64);
        n += __shfl_xor(n, m, 64);
      }
      const int idx = it * 128 + w * 32 + a * 16 + half * 4 + r;
      if (ll == 0 && idx < cnt) P2[(size_t)idx * JS + js] = make_float2(d, n);
    }
}

// Kernel 3: combine 32 splits + log-ratio; last block (threadfence + counter)
// reduces the 32 block partials and writes out. Single dispatch (R7-validated).
__global__ __launch_bounds__(256) void ck_fin(
    const float2* __restrict__ P2, const int* __restrict__ cntp,
    float2* __restrict__ part, int* __restrict__ fc, float* __restrict__ out)
{
  const int cnt = *cntp;
  const int t = threadIdx.x;
  const int idx = blockIdx.x * 256 + t;
  float lsum = 0.f, lcnt = 0.f;
  if (idx < cnt) {
    const float4* p = (const float4*)(P2 + (size_t)idx * JS);  // 256 B
    float d = 0.f, n = 0.f;
#pragma unroll
    for (int u = 0; u < 16; ++u) {
      const float4 v = p[u];
      d += v.x + v.z;
      n += v.y + v.w;
    }
    if (n > 0.f) { lsum = logf(d) - logf(n); lcnt = 1.f; }
  }
  __shared__ float s1[256], s2[256];
  __shared__ int amLast;
  s1[t] = lsum; s2[t] = lcnt;
  __syncthreads();
  for (int s = 128; s > 0; s >>= 1) {
    if (t < s) { s1[t] += s1[t + s]; s2[t] += s2[t + s]; }
    __syncthreads();
  }
  if (t == 0) {
    part[blockIdx.x] = make_float2(s1[0], s2[0]);
    __threadfence();                        // release partial before signaling
    amLast = (atomicAdd(fc, 1) == (int)gridDim.x - 1);
  }
  __syncthreads();
  if (amLast) {
    __threadfence();                        // acquire others' partials
    float s = 0.f, c = 0.f;
    if (t < 32) { const float2 v = part[t]; s = v.x; c = v.y; }
    if (t < 64) {
#pragma unroll
      for (int m = 1; m < 64; m <<= 1) {
        s += __shfl_xor(s, m, 64);
        c += __shfl_xor(c, m, 64);
      }
      if (t == 0) out[0] = (c > 0.f) ? s / fmaxf(c, 1.f) : 0.f;
    }
  }
}

extern "C" void kernel_launch(void* const* d_in, const int* in_sizes, int n_in,
                              void* d_out, int out_size, void* d_ws, size_t ws_size,
                              hipStream_t stream) {
  const float* emb  = (const float*)d_in[0];
  const int* times  = (const int*)d_in[1];
  const int* censor = (const int*)d_in[2];
  float* out = (float*)d_out;

  char* ws = (char*)d_ws;
  short* ZhT    = (short*)(ws + ZH_OFF);
  short* ZmT    = (short*)(ws + ZM_OFF);
  int* rowlist  = (int*)(ws + RL_OFF);
  int* cntp     = (int*)(ws + CNT_OFF);
  int* fc       = (int*)(ws + FC_OFF);
  float2* P2    = (float2*)(ws + P_OFF);
  float2* part  = (float2*)(ws + PART_OFF);

  ck_prep<<<513, 256, 0, stream>>>(emb, censor, ZhT, ZmT, rowlist, cntp, fc);
  ck_main<<<64 * 32, 256, 0, stream>>>(ZhT, ZmT, rowlist, cntp, times, P2);
  ck_fin<<<32, 256, 0, stream>>>(P2, cntp, part, fc, out);
}

// Round 12
// 117.102 us; speedup vs baseline: 2.3744x; 1.0845x over previous
//
#include <hip/hip_runtime.h>
#include <cstdint>

#define BDIM 8192
#define DDIM 128
#define JS 32

// ws layout (bytes)
#define ZH_OFF 0
#define ZM_OFF (2 * 1024 * 1024)
#define RL_OFF (4 * 1024 * 1024)
#define CNT_OFF (RL_OFF + BDIM * 4)          // int cnt
#define FC_OFF (CNT_OFF + 64)                // int fin_counter
#define P_OFF (RL_OFF + 65536)               // float2 P2[BDIM][JS] = 2 MB
#define PART_OFF (P_OFF + BDIM * JS * 8)     // float2 part[32]

typedef __attribute__((ext_vector_type(8))) short bf16x8;   // 8 bf16 = 4 VGPRs
typedef __attribute__((ext_vector_type(4))) float f32x4;

__device__ __forceinline__ short f2bf(float f) {            // RTN-even fp32->bf16
  unsigned u = __float_as_uint(f);
  unsigned r = (u + 0x7fffu + ((u >> 16) & 1u)) >> 16;
  return (short)r;
}
__device__ __forceinline__ float bf2f(short h) {
  return __uint_as_float(((unsigned)(unsigned short)h) << 16);
}
__device__ __forceinline__ void gload_lds16(const void* g, void* l) {
  __builtin_amdgcn_global_load_lds(
      (const __attribute__((address_space(1))) unsigned int*)g,
      (__attribute__((address_space(3))) unsigned int*)l, 16, 0, 0);
}

// Fragment-tiled Z layout (shorts): element (row,k) at
//   (row>>4)*2048 + (k>>5)*512 + ((k>>3)&3)*128 + (row&15)*8 + (k&7)
// 2-pass split: zh = bf16(z), zm = bf16(2z - zh);
//   0.5*(zh.zm' + zm.zh') = exact 3-pass sum (validated: absmax 0.0).
//
// MEASURED RULES:
//  - __launch_bounds__(256,2) caps arch VGPR at 128 -> silent spill. Use plain.
//  - Fused last-block finalize in the GEMM kernel costs ~150us. Keep separate.
//  - B-staging BYTES are the binding resource (R4/R8/R11 all ~51-59us at
//    128 MB staged, ~2.4 TB/s eff.). This round: 256-i blocks halve it to 64 MB.

// Kernel 1: blocks 0..511 normalize + zh/zm split (tiled layout);
// block 512 compacts censor==1 rows (prefix scan) and zeroes fin_counter.
__global__ __launch_bounds__(256) void ck_prep(
    const float* __restrict__ emb, const int* __restrict__ censor,
    short* __restrict__ ZhT, short* __restrict__ ZmT,
    int* __restrict__ rowlist, int* __restrict__ cnt, int* __restrict__ fc)
{
  __shared__ float zl[16][132];
  __shared__ float pr[16][16];
  __shared__ float inv[16];
  __shared__ int wtot[4], woff[4];

  const int t = threadIdx.x;
  if (blockIdx.x == 512) {               // ---- compact branch ----
    const int lane = t & 63, wv = t >> 6;
    const int4* c4 = (const int4*)(censor + t * 32);
    unsigned fm = 0;
#pragma unroll
    for (int q = 0; q < 8; ++q) {
      const int4 v = c4[q];
      fm |= (unsigned)(v.x == 1) << (q * 4 + 0);
      fm |= (unsigned)(v.y == 1) << (q * 4 + 1);
      fm |= (unsigned)(v.z == 1) << (q * 4 + 2);
      fm |= (unsigned)(v.w == 1) << (q * 4 + 3);
    }
    const int loc = __popc(fm);
    int sc = loc;                         // inclusive wave scan
#pragma unroll
    for (int m = 1; m < 64; m <<= 1) {
      const int u = __shfl_up(sc, m, 64);
      if (lane >= m) sc += u;
    }
    if (lane == 63) wtot[wv] = sc;
    __syncthreads();
    if (t == 0) {
      int run = 0;
#pragma unroll
      for (int i = 0; i < 4; ++i) { woff[i] = run; run += wtot[i]; }
      fc[0] = 0;                          // zero finalize counter (ws poisoned)
    }
    __syncthreads();
    int off = woff[wv] + sc - loc;
    for (int u = 0; u < 32; ++u)
      if ((fm >> u) & 1) rowlist[off++] = t * 32 + u;
    if (t == 255) cnt[0] = off;
    return;
  }

  // ---- normalize branch: one 16-row tile per block ----
  const int R = blockIdx.x;
  const int r16 = t >> 4, seg = t & 15;
  const float4* src = (const float4*)(emb + (size_t)(R * 16 + r16) * DDIM + seg * 8);
  const float4 v0 = src[0], v1 = src[1];
  float* zr = &zl[r16][seg * 8];
  zr[0] = v0.x; zr[1] = v0.y; zr[2] = v0.z; zr[3] = v0.w;
  zr[4] = v1.x; zr[5] = v1.y; zr[6] = v1.z; zr[7] = v1.w;
  pr[r16][seg] = v0.x * v0.x + v0.y * v0.y + v0.z * v0.z + v0.w * v0.w +
                 v1.x * v1.x + v1.y * v1.y + v1.z * v1.z + v1.w * v1.w;
  __syncthreads();
  if (t < 16) {
    float ss = 0.f;
#pragma unroll
    for (int s = 0; s < 16; ++s) ss += pr[t][s];
    inv[t] = 1.0f / fmaxf(sqrtf(ss), 1e-12f);   // F.normalize semantics
  }
  __syncthreads();
  const int kc = t >> 6, hf = (t >> 4) & 3, rw = t & 15;
  const float iv = inv[rw];
  const float* zs = &zl[rw][(kc * 4 + hf) * 8];
  short hs[8], ms[8];
#pragma unroll
  for (int j = 0; j < 8; ++j) {
    const float z = zs[j] * iv;
    const short h = f2bf(z);
    hs[j] = h;
    ms[j] = f2bf(2.f * z - bf2f(h));      // zm = bf16(2z - zh)
  }
  const int dst = R * 2048 + t * 8;
  *(bf16x8*)(ZhT + dst) = *(const bf16x8*)hs;
  *(bf16x8*)(ZmT + dst) = *(const bf16x8*)ms;
}

// Kernel 2: MFMA sim + masked exp-sums. Block = 256 i (4 waves x 64) x 256 j
// (4 st-steps of 64 j). Wave tile 64i x 64j (a=4). 2-pass acc = Ah*Bm + Am*Bh
// (scale 5 in epilogue). A-hi resident; A-m streamed per kc (L1-hot). B hi/m
// staged to a 2x32KB LDS double buffer via global_load_lds; R8 cadence:
// barrier -> issue next st's DMA -> compute (only 1 of 4 barriers exposed).
__global__ __launch_bounds__(256) void ck_main(
    const short* __restrict__ ZhT, const short* __restrict__ ZmT,
    const int* __restrict__ rowlist, const int* __restrict__ cntp,
    const int* __restrict__ times, float2* __restrict__ P2)
{
  __shared__ __align__(16) char lds[65536];
  const int cnt = *cntp;
  const int t = threadIdx.x;
  const int b = blockIdx.x;
  const int it = b >> 5;                   // i-tile (256 rows, compacted)
  const int js = b & 31;                   // j-split (256 j)
  if (it * 256 >= cnt) return;
  const int lane = t & 63;
  const int w = t >> 6;
  const int half = lane >> 4;
  const int ll = lane & 15;
  const int jR0 = js * 16;                 // base j16 unit
  const int ibase = it * 256 + w * 64;     // wave's 64 i-rows (compacted idx)

  // A-frag rows (A rows m = ll), a = 0..3
  int rbase[4];
#pragma unroll
  for (int a = 0; a < 4; ++a) {
    int c = ibase + a * 16 + ll;
    if (c >= cnt) c = cnt - 1;             // duplicate valid row; masked at store
    const int r = rowlist[c];
    rbase[a] = (r >> 4) * 2048 + (r & 15) * 8;
  }
  bf16x8 ah[4][4];                         // A-hi resident (64 VGPR)
#pragma unroll
  for (int a = 0; a < 4; ++a)
#pragma unroll
    for (int kc = 0; kc < 4; ++kc)
      ah[a][kc] = *(const bf16x8*)(ZhT + rbase[a] + kc * 512 + half * 128);

  // packed per-(a,r) meta for C/D rows (row = half*4 + r):
  // meta = (ti+364)<<16 | gi ; invalid: gi=0xFFFF, taP=50000 (tests false)
  int meta[4][4];
#pragma unroll
  for (int a = 0; a < 4; ++a)
#pragma unroll
    for (int r = 0; r < 4; ++r) {
      const int idx = ibase + a * 16 + half * 4 + r;
      const bool vi = idx < cnt;
      const int gi = rowlist[vi ? idx : 0];
      const int taP = vi ? (times[gi] + 364) : 50000;
      meta[a][r] = (taP << 16) | (vi ? gi : 0xFFFF);
    }

  float sd[4][4] = {{0.f}}, sn[4][4] = {{0.f}};

  // prologue: stage st=0 into buffer 0 (wave w copies 1KB chunks w*8..w*8+7)
  {
    const int c0 = w * 8;
#pragma unroll
    for (int u = 0; u < 8; ++u) {
      const int c = c0 + u, cp = c & 15;
      const short* src = (c < 16) ? ZhT : ZmT;
      const short* gp = src + (size_t)(jR0 + (cp >> 2)) * 2048 + (cp & 3) * 512 + lane * 8;
      gload_lds16(gp, lds + ((c < 16) ? 0 : 16384) + cp * 1024);
    }
  }

  for (int st = 0; st < 4; ++st) {
    __syncthreads();                       // buf[st&1] resident (drains vmcnt)
    if (st < 3) {                          // stage st+1 into other buffer;
      const int pB = ((st + 1) & 1) * 32768;   // drained by NEXT barrier
      const int c0 = w * 8;
#pragma unroll
      for (int u = 0; u < 8; ++u) {
        const int c = c0 + u, cp = c & 15;
        const short* src = (c < 16) ? ZhT : ZmT;
        const short* gp = src + (size_t)(jR0 + (st + 1) * 4 + (cp >> 2)) * 2048 + (cp & 3) * 512 + lane * 8;
        gload_lds16(gp, lds + pB + ((c < 16) ? 0 : 16384) + cp * 1024);
      }
    }

    const char* L = lds + (st & 1) * 32768;
    f32x4 acc[4][4];                       // 64 AGPR
#pragma unroll
    for (int a = 0; a < 4; ++a)
#pragma unroll
      for (int bb = 0; bb < 4; ++bb) acc[a][bb] = (f32x4){0.f, 0.f, 0.f, 0.f};

#pragma unroll
    for (int kc = 0; kc < 4; ++kc) {
      bf16x8 bh[4], bm[4], amv[4];
#pragma unroll
      for (int bb = 0; bb < 4; ++bb) {
        bh[bb] = *(const bf16x8*)(L + bb * 4096 + kc * 1024 + lane * 16);
        bm[bb] = *(const bf16x8*)(L + 16384 + bb * 4096 + kc * 1024 + lane * 16);
      }
#pragma unroll
      for (int a = 0; a < 4; ++a)          // A-m streamed (L1-hot after st=0)
        amv[a] = *(const bf16x8*)(ZmT + rbase[a] + kc * 512 + half * 128);
#pragma unroll
      for (int a = 0; a < 4; ++a)
#pragma unroll
        for (int bb = 0; bb < 4; ++bb)
          acc[a][bb] = __builtin_amdgcn_mfma_f32_16x16x32_bf16(ah[a][kc], bm[bb], acc[a][bb], 0, 0, 0);
#pragma unroll
      for (int a = 0; a < 4; ++a)
#pragma unroll
        for (int bb = 0; bb < 4; ++bb)
          acc[a][bb] = __builtin_amdgcn_mfma_f32_16x16x32_bf16(amv[a], bh[bb], acc[a][bb], 0, 0, 0);
    }

    // epilogue: s = acc*5 (= cos*10); fixed-offset exp-sums exp(s-10)
    const int jb = js * 256 + st * 64;
    int tJ[4];
#pragma unroll
    for (int bb = 0; bb < 4; ++bb) tJ[bb] = times[jb + bb * 16 + ll];
#pragma unroll
    for (int a = 0; a < 4; ++a)
#pragma unroll
      for (int r = 0; r < 4; ++r) {
        const int m_ = meta[a][r];
        const int gi = m_ & 0xFFFF;
        const unsigned taP = ((unsigned)m_) >> 16;
        float d = 0.f, n = 0.f;
#pragma unroll
        for (int bb = 0; bb < 4; ++bb) {
          const int jgb = jb + bb * 16 + ll;
          float pv = __expf(fmaf(acc[a][bb][r], 5.f, -10.f));
          pv = (gi == jgb) ? 0.f : pv;                 // diagonal mask
          d += pv;
          // |ti-tj|<365  <=>  (u32)(ti+364-tj) <= 728
          n += ((unsigned)(taP - (unsigned)tJ[bb]) <= 728u) ? pv : 0.f;
        }
        sd[a][r] += d;
        sn[a][r] += n;
      }
  }

  // reduce over ll (lane bits 0..3); one float2 store per valid row
#pragma unroll
  for (int a = 0; a < 4; ++a)
#pragma unroll
    for (int r = 0; r < 4; ++r) {
      float d = sd[a][r], n = sn[a][r];
#pragma unroll
      for (int m = 1; m <= 8; m <<= 1) {
        d += __shfl_xor(d, m, 64);
        n += __shfl_xor(n, m, 64);
      }
      const int idx = ibase + a * 16 + half * 4 + r;
      if (ll == 0 && idx < cnt) P2[(size_t)idx * JS + js] = make_float2(d, n);
    }
}

// Kernel 3: combine 32 splits + log-ratio; last block (threadfence + counter)
// reduces the 32 block partials and writes out. Single dispatch (R7-validated).
__global__ __launch_bounds__(256) void ck_fin(
    const float2* __restrict__ P2, const int* __restrict__ cntp,
    float2* __restrict__ part, int* __restrict__ fc, float* __restrict__ out)
{
  const int cnt = *cntp;
  const int t = threadIdx.x;
  const int idx = blockIdx.x * 256 + t;
  float lsum = 0.f, lcnt = 0.f;
  if (idx < cnt) {
    const float4* p = (const float4*)(P2 + (size_t)idx * JS);  // 256 B
    float d = 0.f, n = 0.f;
#pragma unroll
    for (int u = 0; u < 16; ++u) {
      const float4 v = p[u];
      d += v.x + v.z;
      n += v.y + v.w;
    }
    if (n > 0.f) { lsum = logf(d) - logf(n); lcnt = 1.f; }
  }
  __shared__ float s1[256], s2[256];
  __shared__ int amLast;
  s1[t] = lsum; s2[t] = lcnt;
  __syncthreads();
  for (int s = 128; s > 0; s >>= 1) {
    if (t < s) { s1[t] += s1[t + s]; s2[t] += s2[t + s]; }
    __syncthreads();
  }
  if (t == 0) {
    part[blockIdx.x] = make_float2(s1[0], s2[0]);
    __threadfence();                        // release partial before signaling
    amLast = (atomicAdd(fc, 1) == (int)gridDim.x - 1);
  }
  __syncthreads();
  if (amLast) {
    __threadfence();                        // acquire others' partials
    float s = 0.f, c = 0.f;
    if (t < 32) { const float2 v = part[t]; s = v.x; c = v.y; }
    if (t < 64) {
#pragma unroll
      for (int m = 1; m < 64; m <<= 1) {
        s += __shfl_xor(s, m, 64);
        c += __shfl_xor(c, m, 64);
      }
      if (t == 0) out[0] = (c > 0.f) ? s / fmaxf(c, 1.f) : 0.f;
    }
  }
}

extern "C" void kernel_launch(void* const* d_in, const int* in_sizes, int n_in,
                              void* d_out, int out_size, void* d_ws, size_t ws_size,
                              hipStream_t stream) {
  const float* emb  = (const float*)d_in[0];
  const int* times  = (const int*)d_in[1];
  const int* censor = (const int*)d_in[2];
  float* out = (float*)d_out;

  char* ws = (char*)d_ws;
  short* ZhT    = (short*)(ws + ZH_OFF);
  short* ZmT    = (short*)(ws + ZM_OFF);
  int* rowlist  = (int*)(ws + RL_OFF);
  int* cntp     = (int*)(ws + CNT_OFF);
  int* fc       = (int*)(ws + FC_OFF);
  float2* P2    = (float2*)(ws + P_OFF);
  float2* part  = (float2*)(ws + PART_OFF);

  ck_prep<<<513, 256, 0, stream>>>(emb, censor, ZhT, ZmT, rowlist, cntp, fc);
  ck_main<<<32 * 32, 256, 0, stream>>>(ZhT, ZmT, rowlist, cntp, times, P2);
  ck_fin<<<32, 256, 0, stream>>>(P2, cntp, part, fc, out);
}